// Round 6
// baseline (115.011 us; speedup 1.0000x reference)
//
#include <hip/hip_runtime.h>

// KPN per-pixel 5x5 predicted convolution, channels-last fp32.
// out[b,h,w,c] = sum_{i,j} feat[b,h+i-2,w+j-2,c] * kernel[b,h,w,i*5+j] + bias[c]
//
// Round 6: feat tile staged in LDS (pivot from global-latency structure).
//  - Each block: 4 output rows x 32 cols x all 32 ch. Feat tile with halo
//    (8 x 36 x 32ch = 36.9 KB) staged ONCE -> 9 global float4/thread instead
//    of 40 (R5 re-read each feat elem ~5x through the VMEM pipe; latency-
//    bound at 2 waves/SIMD). Boundary zeroing folded into staging: compute
//    loop is maskless FMAs on LDS data.
//  - Feat LDS layout [row][col][32ch] UNPADDED: float4 reads are 16B-aligned;
//    for each wL the 8 cg-lanes' 4 words sweep all 32 banks (same phase
//    structure as contiguous b128, ~85 B/cyc, no conflicts).
//  - Weights in skA (taps j=0..3 as float4) + skB (tap j=4): aligned b128+b32,
//    wL-lanes on distinct banks, cg-lanes broadcast.
//  - LDS 49.7 KB -> 3 blocks/CU; __launch_bounds__(256,3) caps ~168 VGPR
//    (need ~90) -> no scratch spill (R3/R4 lesson), decent TLP (R5 lesson).

#define BB 4
#define HH 256
#define WW 256
#define CC 32
#define KK 5
#define VH 4                   // output rows per thread/block
#define TW 32                  // tile width (pixels)
#define TPB 256
#define TROWS (VH + KK - 1)    // 8 feat rows in tile
#define TCOLS (TW + KK - 1)    // 36 feat cols in tile

__global__ __launch_bounds__(TPB, 3) void kpn_conv_kernel(
    const float* __restrict__ feat,
    const float* __restrict__ kern,
    const float* __restrict__ bias,
    float* __restrict__ out)
{
    __shared__ float  sf[TROWS * TCOLS * CC];   // 9216 fl = 36.9 KB
    __shared__ float4 skA[VH * KK * TW];        // 640 f4 = 10.2 KB (taps j0..3)
    __shared__ float  skB[VH * KK * TW];        // 640 fl =  2.6 KB (tap j4)

    const int t  = threadIdx.x;
    const int bw = blockIdx.x & 7;           // W/TW = 8
    const int bh = (blockIdx.x >> 3) & 63;   // H/VH = 64
    const int b  = blockIdx.x >> 9;          // B = 4
    const int h0 = bh * VH;
    const int w0 = bw * TW;

    const float* fb = feat + (((size_t)b) << 16) * CC;

    // ---- Stage feat tile (with halo), zeroing out-of-image elements. ----
    // 8 rows x 36 cols x 32 ch = 2304 float4; 9 per thread; global-contiguous
    // within each row segment -> coalesced; LDS writes contiguous -> optimal.
    #pragma unroll
    for (int it = 0; it < (TROWS * TCOLS * CC / 4) / TPB; ++it) {  // 9
        int e    = t + it * TPB;
        int row  = e / (TCOLS * CC / 4);         // /288
        int rem  = e - row * (TCOLS * CC / 4);
        int col  = rem >> 3;                     // 8 float4 per col
        int cho  = (rem & 7) << 2;
        int hraw = h0 + row - (KK / 2);
        int wraw = w0 + col - (KK / 2);
        bool v   = ((unsigned)hraw < (unsigned)HH) && ((unsigned)wraw < (unsigned)WW);
        int hc   = min(max(hraw, 0), HH - 1);
        int wc   = min(max(wraw, 0), WW - 1);
        float4 f4 = *(const float4*)(fb + ((((size_t)hc << 8) + wc) << 5) + cho);
        if (!v) { f4.x = 0.f; f4.y = 0.f; f4.z = 0.f; f4.w = 0.f; }
        *(float4*)(&sf[(row * TCOLS + col) * CC + cho]) = f4;
    }

    // ---- Stage weights into skA/skB (coalesced global scalar reads). ----
    {
        const float* kb = kern + (size_t)((b * HH + h0) * WW + w0) * (KK * KK);
        #pragma unroll
        for (int it = 0; it < 13; ++it) {
            int idx = t + it * TPB;
            if (idx < VH * TW * KK * KK) {           // 3200
                int oh  = idx / (TW * KK * KK);      // /800
                int rem = idx - oh * (TW * KK * KK);
                int wl  = rem / (KK * KK);           // /25
                int tap = rem - wl * (KK * KK);
                int i   = tap / KK;
                int j   = tap - i * KK;
                float val = kb[(size_t)oh * WW * (KK * KK) + rem];
                int slot  = (oh * KK + i) * TW + wl;
                if (j < 4) ((float*)skA)[slot * 4 + j] = val;
                else       skB[slot] = val;
            }
        }
    }
    __syncthreads();

    const int cg = (t & 7) * 4;   // channel group
    const int wL = t >> 3;        // 0..31

    const float4 bz = *(const float4*)(bias + cg);
    float4 acc[VH];
    #pragma unroll
    for (int oh = 0; oh < VH; ++oh) acc[oh] = bz;

    // ---- Maskless compute: 8 tile rows, 5-col window from LDS. ----
    #pragma unroll
    for (int r = 0; r < TROWS; ++r) {
        float4 f[KK];
        #pragma unroll
        for (int j = 0; j < KK; ++j)
            f[j] = *(const float4*)(&sf[(r * TCOLS + wL + j) * CC + cg]);

        #pragma unroll
        for (int oh = 0; oh < VH; ++oh) {
            const int i = r - oh;                  // kernel row
            if (i >= 0 && i < KK) {                // compile-time after unroll
                const int slot = (oh * KK + i) * TW + wL;
                const float4 wa = skA[slot];
                const float  wb = skB[slot];
                acc[oh].x += f[0].x*wa.x + f[1].x*wa.y + f[2].x*wa.z + f[3].x*wa.w + f[4].x*wb;
                acc[oh].y += f[0].y*wa.x + f[1].y*wa.y + f[2].y*wa.z + f[3].y*wa.w + f[4].y*wb;
                acc[oh].z += f[0].z*wa.x + f[1].z*wa.y + f[2].z*wa.z + f[3].z*wa.w + f[4].z*wb;
                acc[oh].w += f[0].w*wa.x + f[1].w*wa.y + f[2].w*wa.z + f[3].w*wa.w + f[4].w*wb;
            }
        }
    }

    // ---- Coalesced stores: 4 rows x 1 KiB per wave. ----
    #pragma unroll
    for (int oh = 0; oh < VH; ++oh) {
        const size_t pix = (size_t)(b * HH + h0 + oh) * WW + (w0 + wL);
        *(float4*)(out + pix * CC + cg) = acc[oh];
    }
}

extern "C" void kernel_launch(void* const* d_in, const int* in_sizes, int n_in,
                              void* d_out, int out_size, void* d_ws, size_t ws_size,
                              hipStream_t stream) {
    const float* feat = (const float*)d_in[0];
    const float* kern = (const float*)d_in[1];
    const float* bias = (const float*)d_in[2];
    float* out = (float*)d_out;

    dim3 grid(BB * (HH / VH) * (WW / TW));  // 2048 blocks
    dim3 block(TPB);
    kpn_conv_kernel<<<grid, block, 0, stream>>>(feat, kern, bias, out);
}

// Round 7
// 105.024 us; speedup vs baseline: 1.0951x; 1.0951x over previous
//
#include <hip/hip_runtime.h>

// KPN per-pixel 5x5 predicted convolution, channels-last fp32.
// out[b,h,w,c] = sum_{i,j} feat[b,h+i-2,w+j-2,c] * kernel[b,h,w,i*5+j] + bias[c]
//
// Round 7 = Round 6 tile structure with ASYNC staging:
//  - R6 diagnosis: VGPR=84 => compiler staged global->VGPR->LDS with a
//    vmcnt(0) round-trip per load; ~22 serialized ~900-cyc latencies/block
//    (Tblock ~33k cyc for ~4k cyc of work). Fix: __builtin_amdgcn_global_load_lds
//    width=16 (async DMA, no VGPR payload). All 49 issues/block go out
//    back-to-back; one drain at __syncthreads.
//  - Async LDS dest is wave-uniform-base + lane*16 => LDS layouts must be
//    lane-contiguous: feat [row][col][32ch] unpadded, weights raw [oh][px][25].
//  - Async can't zero OOB lanes: halo loads use CLAMPED addresses; edge
//    blocks (block-uniform branch) zero the OOB LDS rows/cols post-barrier.
//  - Weights read as scalars wp[0..4] (compiler merges to ds_read2_b32);
//    wL-lanes stride 25 floats -> distinct banks; cg-lanes broadcast.

#define BB 4
#define HH 256
#define WW 256
#define CC 32
#define KK 5
#define VH 4                    // output rows per block
#define TW 32                   // tile width (pixels)
#define TPB 256
#define TROWS (VH + KK - 1)     // 8 feat rows
#define TCOLS (TW + KK - 1)     // 36 feat cols
#define SF_F4 (TROWS * TCOLS * CC / 4)   // 2304 float4 = 36.9 KB
#define SK_F4 832                        // 800 float4 weights + tail pad
#define NQF 36                  // feat async issues (2304/64)
#define NQ  49                  // + 13 weight issues (832/64)

typedef __attribute__((address_space(1))) const void gvoid_t;
typedef __attribute__((address_space(3))) void svoid_t;

__global__ __launch_bounds__(TPB, 3) void kpn_conv_kernel(
    const float* __restrict__ feat,
    const float* __restrict__ kern,
    const float* __restrict__ bias,
    float* __restrict__ out)
{
    __shared__ float4 sb[SF_F4 + SK_F4];   // 50.2 KB -> 3 blocks/CU

    const int t    = threadIdx.x;
    const int lane = t & 63;
    const int wave = t >> 6;

    const int bw = blockIdx.x & 7;           // W/TW = 8
    const int bh = (blockIdx.x >> 3) & 63;   // H/VH = 64
    const int b  = blockIdx.x >> 9;          // B = 4
    const int h0 = bh * VH;
    const int w0 = bw * TW;

    const float* fb = feat + (((size_t)b) << 16) * CC;
    const float* kb = kern + (size_t)((b * HH + h0) * WW + w0) * (KK * KK);

    // ---- Async staging: 49 wave-issues, all in flight, zero VGPR payload. ----
    for (int q = wave; q < NQ; q += TPB / 64) {
        if (q < NQF) {
            // feat: LDS float4 slot e = q*64+lane -> (row, col, c4)
            int e   = (q << 6) + lane;
            int row = e / (TCOLS * CC / 4);          // /288
            int rem = e - row * (TCOLS * CC / 4);
            int col = rem >> 3;
            int c4  = rem & 7;
            int hc  = min(max(h0 + row - (KK / 2), 0), HH - 1);
            int wc  = min(max(w0 + col - (KK / 2), 0), WW - 1);
            const float* gp = fb + ((((size_t)hc << 8) + wc) << 5) + (c4 << 2);
            __builtin_amdgcn_global_load_lds((gvoid_t*)gp,
                                             (svoid_t*)(sb + (q << 6)),
                                             16, 0, 0);
        } else {
            // weights: raw contiguous copy; tail lanes (e>=800) clamp into pad.
            int e   = ((q - NQF) << 6) + lane;
            int e4  = min(e, (VH * TW * KK * KK / 4) - 1);   // 799
            int oh  = e4 / 200;                              // 200 f4 per oh
            int off = (e4 - oh * 200) << 2;
            const float* gp = kb + (size_t)oh * (WW * KK * KK) + off;
            __builtin_amdgcn_global_load_lds((gvoid_t*)gp,
                                             (svoid_t*)(sb + SF_F4 + ((q - NQF) << 6)),
                                             16, 0, 0);
        }
    }
    __syncthreads();   // drains vmcnt (covers global_load_lds)

    // ---- Edge blocks only: zero OOB halo entries (block-uniform branch). ----
    const bool wlo = (w0 == 0), whi = (w0 == WW - TW);
    if (h0 == 0 || h0 == HH - VH || wlo || whi) {
        const float4 z = make_float4(0.f, 0.f, 0.f, 0.f);
        #pragma unroll
        for (int r = 0; r < TROWS; ++r) {
            int hraw = h0 + r - (KK / 2);
            if (hraw < 0 || hraw >= HH) {            // uniform per block
                for (int s = t; s < TCOLS * CC / 4; s += TPB)   // 288 slots
                    sb[r * (TCOLS * CC / 4) + s] = z;
            }
        }
        if (wlo && t < 128) {   // cols 0,1: 8 rows x 2 cols x 8 f4
            int r = t >> 4, c = (t >> 3) & 1, c4 = t & 7;
            sb[r * (TCOLS * CC / 4) + c * 8 + c4] = z;
        }
        if (whi && t < 128) {   // cols 34,35
            int r = t >> 4, c = (TCOLS - 2) + ((t >> 3) & 1), c4 = t & 7;
            sb[r * (TCOLS * CC / 4) + c * 8 + c4] = z;
        }
        __syncthreads();
    }

    // ---- Maskless compute from LDS. ----
    const int cg = (t & 7) << 2;   // channel group
    const int wL = t >> 3;         // 0..31
    const float* sf  = (const float*)sb;
    const float* skw = (const float*)(sb + SF_F4);

    const float4 bz = *(const float4*)(bias + cg);
    float4 acc[VH];
    #pragma unroll
    for (int oh = 0; oh < VH; ++oh) acc[oh] = bz;

    #pragma unroll
    for (int r = 0; r < TROWS; ++r) {
        float4 f[KK];
        #pragma unroll
        for (int j = 0; j < KK; ++j)
            f[j] = *(const float4*)(sf + (r * TCOLS + wL + j) * CC + cg);

        #pragma unroll
        for (int oh = 0; oh < VH; ++oh) {
            const int i = r - oh;                    // kernel row
            if (i >= 0 && i < KK) {                  // compile-time after unroll
                const float* wp = skw + (oh * TW + wL) * (KK * KK) + i * KK;
                const float wg0 = wp[0], wg1 = wp[1], wg2 = wp[2],
                            wg3 = wp[3], wg4 = wp[4];
                acc[oh].x += f[0].x*wg0 + f[1].x*wg1 + f[2].x*wg2 + f[3].x*wg3 + f[4].x*wg4;
                acc[oh].y += f[0].y*wg0 + f[1].y*wg1 + f[2].y*wg2 + f[3].y*wg3 + f[4].y*wg4;
                acc[oh].z += f[0].z*wg0 + f[1].z*wg1 + f[2].z*wg2 + f[3].z*wg3 + f[4].z*wg4;
                acc[oh].w += f[0].w*wg0 + f[1].w*wg1 + f[2].w*wg2 + f[3].w*wg3 + f[4].w*wg4;
            }
        }
    }

    // ---- Coalesced stores: 4 rows x 1 KiB per wave. ----
    #pragma unroll
    for (int oh = 0; oh < VH; ++oh) {
        const size_t pix = (size_t)(b * HH + h0 + oh) * WW + (w0 + wL);
        *(float4*)(out + pix * CC + cg) = acc[oh];
    }
}

extern "C" void kernel_launch(void* const* d_in, const int* in_sizes, int n_in,
                              void* d_out, int out_size, void* d_ws, size_t ws_size,
                              hipStream_t stream) {
    const float* feat = (const float*)d_in[0];
    const float* kern = (const float*)d_in[1];
    const float* bias = (const float*)d_in[2];
    float* out = (float*)d_out;

    dim3 grid(BB * (HH / VH) * (WW / TW));  // 2048 blocks
    dim3 block(TPB);
    kpn_conv_kernel<<<grid, block, 0, stream>>>(feat, kern, bias, out);
}